// Round 1
// baseline (17.283 us; speedup 1.0000x reference)
//
#include <hip/hip_runtime.h>

#define DD 200
#define UU 32
#define TT 4
#define AA 20
#define NN 10

__global__ __launch_bounds__(256) void gatne_kernel(
    const int* __restrict__ train_inputs,
    const int* __restrict__ train_types,
    const int* __restrict__ node_neigh,
    const float* __restrict__ node_emb,
    const float* __restrict__ node_type_emb,
    const float* __restrict__ trans_w,
    const float* __restrict__ trans_s1,
    const float* __restrict__ trans_s2,
    float* __restrict__ out)
{
    const int b   = blockIdx.x;
    const int tid = threadIdx.x;

    __shared__ float nte[TT][UU];      // node_type_embed (summed over N)
    __shared__ float partial[8][UU];   // per-half partial sums
    __shared__ float h[TT][AA];
    __shared__ float att[TT];
    __shared__ float agg[UU];
    __shared__ int   idx[TT][NN];
    __shared__ float wsum[5];
    __shared__ int   sinfo[2];         // [0]=type, [1]=input node

    if (tid < 2) sinfo[tid] = (tid == 0) ? train_types[b] : train_inputs[b];
    if (tid < TT*NN) idx[tid/NN][tid%NN] = node_neigh[(size_t)b*TT*NN + tid];
    __syncthreads();

    const int type = sinfo[0];

    // ---- gather neighbor type-embeddings and sum over N ----
    // 256 threads = 8 groups of 32 lanes; group g handles (t = g&3, half = g>>2).
    // Lanes of a group read 32 consecutive floats (128 B) per row: coalesced.
    {
        const int grp  = tid >> 5;
        const int u    = tid & 31;
        const int t    = grp & 3;
        const int half = grp >> 2;
        float acc = 0.f;
        #pragma unroll
        for (int k = 0; k < 5; ++k) {
            const int n = half * 5 + k;
            const size_t node = (size_t)idx[t][n];
            acc += node_type_emb[node * (TT*UU) + t*UU + u];
        }
        partial[grp][u] = acc;
    }
    __syncthreads();
    if (tid < TT*UU) {
        const int t = tid >> 5, u = tid & 31;
        nte[t][u] = partial[t][u] + partial[t + 4][u];
    }
    __syncthreads();

    // ---- h = tanh(nte @ s1[type])   [T][A] ----
    if (tid < TT*AA) {
        const int t = tid / AA, a = tid % AA;
        const float* w = trans_s1 + (size_t)type * UU * AA;
        float acc = 0.f;
        #pragma unroll
        for (int u = 0; u < UU; ++u) acc += nte[t][u] * w[u*AA + a];
        h[t][a] = tanhf(acc);
    }
    __syncthreads();

    // ---- logits[t] = h[t] . s2[type] ----
    if (tid < TT) {
        const float* w2 = trans_s2 + (size_t)type * AA;
        float acc = 0.f;
        #pragma unroll
        for (int a = 0; a < AA; ++a) acc += h[tid][a] * w2[a];
        att[tid] = acc;
    }
    __syncthreads();

    // ---- softmax over T=4 ----
    if (tid == 0) {
        float m = fmaxf(fmaxf(att[0], att[1]), fmaxf(att[2], att[3]));
        float e0 = expf(att[0] - m), e1 = expf(att[1] - m),
              e2 = expf(att[2] - m), e3 = expf(att[3] - m);
        float inv = 1.f / (e0 + e1 + e2 + e3);
        att[0] = e0*inv; att[1] = e1*inv; att[2] = e2*inv; att[3] = e3*inv;
    }
    __syncthreads();

    // ---- agg[u] = sum_t att[t] * nte[t][u] ----
    if (tid < UU) {
        float acc = 0.f;
        #pragma unroll
        for (int t = 0; t < TT; ++t) acc += att[t] * nte[t][tid];
        agg[tid] = acc;
    }
    __syncthreads();

    // ---- out[d] = node_emb[input][d] + sum_u agg[u]*trans_w[type][u][d]; L2-normalize ----
    float val = 0.f;
    if (tid < DD) {
        const float* w = trans_w + (size_t)type * UU * DD;
        float acc = node_emb[(size_t)sinfo[1] * DD + tid];
        #pragma unroll 8
        for (int u = 0; u < UU; ++u) acc += agg[u] * w[u*DD + tid];
        val = acc;
    }
    float sq = val * val;
    #pragma unroll
    for (int off = 32; off > 0; off >>= 1) sq += __shfl_down(sq, off);
    if ((tid & 63) == 0) wsum[tid >> 6] = sq;
    __syncthreads();
    if (tid == 0) {
        float s = wsum[0] + wsum[1] + wsum[2] + wsum[3];
        wsum[4] = 1.f / fmaxf(sqrtf(s), 1e-12f);
    }
    __syncthreads();
    if (tid < DD) out[(size_t)b*DD + tid] = val * wsum[4];
}

extern "C" void kernel_launch(void* const* d_in, const int* in_sizes, int n_in,
                              void* d_out, int out_size, void* d_ws, size_t ws_size,
                              hipStream_t stream) {
    const int*   train_inputs  = (const int*)d_in[0];
    const int*   train_types   = (const int*)d_in[1];
    const int*   node_neigh    = (const int*)d_in[2];
    const float* node_emb      = (const float*)d_in[3];
    const float* node_type_emb = (const float*)d_in[4];
    const float* trans_w       = (const float*)d_in[5];
    const float* trans_s1      = (const float*)d_in[6];
    const float* trans_s2      = (const float*)d_in[7];
    float* out = (float*)d_out;

    const int B = in_sizes[0];  // 4096
    gatne_kernel<<<B, 256, 0, stream>>>(train_inputs, train_types, node_neigh,
                                        node_emb, node_type_emb, trans_w,
                                        trans_s1, trans_s2, out);
}

// Round 2
// 15.102 us; speedup vs baseline: 1.1445x; 1.1445x over previous
//
#include <hip/hip_runtime.h>

#define DD 200
#define UU 32
#define TT 4
#define AA 20
#define NN 10
#define WPB 4          // waves (batch elements) per block

// per-wave LDS float layout:
//   nte:    [0, 144)    4 rows of stride 36 (bank-conflict-free, 16B aligned)
//   h:      [144, 224)  4*20
//   logits: [224, 228)
#define NTE_STRIDE 36
#define H_OFF 144
#define LG_OFF 224
#define WS_FLOATS 240

__global__ __launch_bounds__(256) void gatne_kernel(
    const int* __restrict__ train_inputs,
    const int* __restrict__ train_types,
    const int* __restrict__ node_neigh,
    const float* __restrict__ node_emb,
    const float* __restrict__ node_type_emb,
    const float* __restrict__ trans_w,
    const float* __restrict__ trans_s1,
    const float* __restrict__ trans_s2,
    float* __restrict__ out,
    int B)
{
    const int tid  = threadIdx.x;
    const int wid  = tid >> 6;
    const int lane = tid & 63;
    const int b    = blockIdx.x * WPB + wid;

    __shared__ float smem[WPB][WS_FLOATS];
    float* ws = smem[wid];

    if (b >= B) return;   // whole wave exits together (b is wave-uniform)

    // ---- per-lane gather mapping: 8 lanes per 128B row ----
    const int g    = lane >> 3;        // 0..7
    const int sub  = lane & 7;         // 0..7 (u-quad within row)
    const int gt   = g >> 1;           // this lane's t
    const int nb   = (g & 1) * 5;      // n-half base

    // lane-private neighbor index (lanes 0..39), distributed later via shfl
    int myidx = 0;
    if (lane < TT * NN) myidx = node_neigh[(size_t)b * (TT * NN) + lane];
    const int type  = train_types[b];   // uniform-address loads (broadcast)
    const int input = train_inputs[b];

    // ---- gather neighbor type-embeddings, sum over N ----
    float4 acc = make_float4(0.f, 0.f, 0.f, 0.f);
    #pragma unroll
    for (int i = 0; i < 5; ++i) {
        const int r    = gt * NN + nb + i;
        const int node = __shfl(myidx, r);
        const float4 v = *(const float4*)(node_type_emb +
                            (size_t)node * (TT * UU) + gt * UU + sub * 4);
        acc.x += v.x; acc.y += v.y; acc.z += v.z; acc.w += v.w;
    }
    // combine the two n-halves (groups g and g^1 share t)
    acc.x += __shfl_xor(acc.x, 8);
    acc.y += __shfl_xor(acc.y, 8);
    acc.z += __shfl_xor(acc.z, 8);
    acc.w += __shfl_xor(acc.w, 8);
    if ((g & 1) == 0)
        *(float4*)(ws + gt * NTE_STRIDE + sub * 4) = acc;
    asm volatile("s_waitcnt lgkmcnt(0)" ::: "memory");

    // ---- h[t][a] = tanh( sum_u nte[t][u] * s1[u][a] ) ----
    const float* s1g = trans_s1 + (size_t)type * (UU * AA);
    {
        const int t = lane >> 4, a = lane & 15;          // a = 0..15, all t
        float hacc = 0.f;
        #pragma unroll
        for (int u = 0; u < UU; ++u)
            hacc += ws[t * NTE_STRIDE + u] * s1g[u * AA + a];
        ws[H_OFF + t * AA + a] = tanhf(hacc);
    }
    if (lane < 16) {                                     // a = 16..19, all t
        const int t = lane >> 2, a = 16 + (lane & 3);
        float hacc = 0.f;
        #pragma unroll
        for (int u = 0; u < UU; ++u)
            hacc += ws[t * NTE_STRIDE + u] * s1g[u * AA + a];
        ws[H_OFF + t * AA + a] = tanhf(hacc);
    }
    asm volatile("s_waitcnt lgkmcnt(0)" ::: "memory");

    // ---- logits[t] = h[t] . s2 ----
    if (lane < TT) {
        const float* s2g = trans_s2 + (size_t)type * AA;
        float lacc = 0.f;
        #pragma unroll
        for (int k = 0; k < 5; ++k) {
            const float4 h4 = *(const float4*)(ws + H_OFF + lane * AA + 4 * k);
            const float4 s4 = *(const float4*)(s2g + 4 * k);
            lacc += h4.x * s4.x + h4.y * s4.y + h4.z * s4.z + h4.w * s4.w;
        }
        ws[LG_OFF + lane] = lacc;
    }
    asm volatile("s_waitcnt lgkmcnt(0)" ::: "memory");

    // ---- softmax over T=4, redundantly in every lane ----
    const float4 lg = *(const float4*)(ws + LG_OFF);
    const float m  = fmaxf(fmaxf(lg.x, lg.y), fmaxf(lg.z, lg.w));
    float e0 = expf(lg.x - m), e1 = expf(lg.y - m),
          e2 = expf(lg.z - m), e3 = expf(lg.w - m);
    const float inv = 1.f / (e0 + e1 + e2 + e3);
    e0 *= inv; e1 *= inv; e2 *= inv; e3 *= inv;

    // ---- agg[u], u = lane&31 (duplicated in both half-waves) ----
    const int u = lane & 31;
    const float aggu = e0 * ws[0 * NTE_STRIDE + u] + e1 * ws[1 * NTE_STRIDE + u]
                     + e2 * ws[2 * NTE_STRIDE + u] + e3 * ws[3 * NTE_STRIDE + u];

    // ---- out = node_emb[input] + agg @ trans_w[type]; L2 normalize ----
    float4 o = make_float4(0.f, 0.f, 0.f, 0.f);
    const float* wg = trans_w + (size_t)type * (UU * DD);
    if (lane < DD / 4) {      // 50 lanes, d0 = lane*4
        o = *(const float4*)(node_emb + (size_t)input * DD + lane * 4);
        #pragma unroll 8
        for (int uu = 0; uu < UU; ++uu) {
            const float a  = __shfl(aggu, uu);
            const float4 w4 = *(const float4*)(wg + uu * DD + lane * 4);
            o.x += a * w4.x; o.y += a * w4.y; o.z += a * w4.z; o.w += a * w4.w;
        }
    }
    float sq = o.x * o.x + o.y * o.y + o.z * o.z + o.w * o.w;
    #pragma unroll
    for (int off = 1; off < 64; off <<= 1) sq += __shfl_xor(sq, off);
    const float invn = 1.f / fmaxf(sqrtf(sq), 1e-12f);
    if (lane < DD / 4) {
        const float4 r = make_float4(o.x * invn, o.y * invn, o.z * invn, o.w * invn);
        *(float4*)(out + (size_t)b * DD + lane * 4) = r;
    }
}

extern "C" void kernel_launch(void* const* d_in, const int* in_sizes, int n_in,
                              void* d_out, int out_size, void* d_ws, size_t ws_size,
                              hipStream_t stream) {
    const int*   train_inputs  = (const int*)d_in[0];
    const int*   train_types   = (const int*)d_in[1];
    const int*   node_neigh    = (const int*)d_in[2];
    const float* node_emb      = (const float*)d_in[3];
    const float* node_type_emb = (const float*)d_in[4];
    const float* trans_w       = (const float*)d_in[5];
    const float* trans_s1      = (const float*)d_in[6];
    const float* trans_s2      = (const float*)d_in[7];
    float* out = (float*)d_out;

    const int B = in_sizes[0];  // 4096
    const int grid = (B + WPB - 1) / WPB;
    gatne_kernel<<<grid, 256, 0, stream>>>(train_inputs, train_types, node_neigh,
                                           node_emb, node_type_emb, trans_w,
                                           trans_s1, trans_s2, out, B);
}